// Round 5
// baseline (302.953 us; speedup 1.0000x reference)
//
#include <hip/hip_runtime.h>
#include <cstddef>
#include <cstdint>

#define H 1024
#define V 15000
#define NE 4
#define B 32
#define S 2048
#define EPS 1e-6f
#define CH 32
#define T0 64   // S / CH
#define SB 8    // timesteps per register sub-block (scanA/fuseCD)
#define NVT 938 // ceil(V/16): 16 vocab rows per block in k_logits

typedef unsigned short u16;
typedef __attribute__((ext_vector_type(8))) short bf16x8;
typedef __attribute__((ext_vector_type(4))) float f32x4;

__device__ __forceinline__ float wave_sum(float x) {
#pragma unroll
  for (int off = 32; off > 0; off >>= 1) x += __shfl_down(x, off);
  return x;
}

__device__ __forceinline__ float bf2f(u16 u) {
  union { uint32_t i; float f; } x;
  x.i = ((uint32_t)u) << 16;
  return x.f;
}

// unpack a dword holding 2 bf16 (little-endian: lo = element 0, hi = element 1)
__device__ __forceinline__ float bflo(uint32_t u) {
  union { uint32_t i; float f; } x;
  x.i = u << 16;
  return x.f;
}
__device__ __forceinline__ float bfhi(uint32_t u) {
  union { uint32_t i; float f; } x;
  x.i = u & 0xFFFF0000u;
  return x.f;
}

__device__ __forceinline__ u16 f2bf(float f) {
  union { float f; uint32_t i; } x;
  x.f = f;
  const uint32_t u = x.i;
  return (u16)((u + 0x7FFFu + ((u >> 16) & 1u)) >> 16);  // RNE
}

__device__ __forceinline__ float uasf(uint32_t u) {
  union { uint32_t i; float f; } x;
  x.i = u;
  return x.f;
}
__device__ __forceinline__ uint32_t fasu(float f) {
  union { float f; uint32_t i; } x;
  x.f = f;
  return x.i;
}

// Split two fp32 into a packed bf16-hi dword (truncation) and a packed
// bf16-lo dword (RNE of the exact residual). hi+lo reproduces x to ~2^-17.
__device__ __forceinline__ void split2(float x0, float x1, uint32_t& hp,
                                       uint32_t& lp) {
  const uint32_t u0 = fasu(x0), u1 = fasu(x1);
  hp = (u0 >> 16) | (u1 & 0xFFFF0000u);
  const float l0 = x0 - uasf(u0 & 0xFFFF0000u);
  const float l1 = x1 - uasf(u1 & 0xFFFF0000u);
  asm("v_cvt_pk_bf16_f32 %0, %1, %2" : "=v"(lp) : "v"(l0), "v"(l1));
}

// K1: per-vocab-row inverse RMS of embedding; also mirrors emb -> bf16.
__global__ __launch_bounds__(256) void k_vocab(const float* __restrict__ emb,
                                               float* __restrict__ invr1,
                                               u16* __restrict__ embh) {
  const int gw = (blockIdx.x * blockDim.x + threadIdx.x) >> 6;  // row
  const int lane = threadIdx.x & 63;
  if (gw >= V) return;
  const float4* row = (const float4*)(emb + (size_t)gw * H);
  float s = 0.f;
#pragma unroll
  for (int j = 0; j < 4; ++j) {
    const float4 f = row[lane + 64 * j];
    s += f.x * f.x + f.y * f.y + f.z * f.z + f.w * f.w;
    if (embh) {
      ushort4 h4;
      h4.x = f2bf(f.x); h4.y = f2bf(f.y); h4.z = f2bf(f.z); h4.w = f2bf(f.w);
      ((ushort4*)(embh + (size_t)gw * H))[lane + 64 * j] = h4;
    }
  }
  s = wave_sum(s);
  if (lane == 0) invr1[gw] = rsqrtf(s * (1.f / H) + EPS);
}

// Bucket b's by expert id (serial, trivial).
__global__ void k_bucket(const int* __restrict__ experts,
                         int* __restrict__ elist, int* __restrict__ ecnt) {
  if (threadIdx.x == 0 && blockIdx.x == 0) {
    int c[NE] = {0, 0, 0, 0};
    for (int b = 0; b < B; ++b) {
      const int e = experts[b];
      elist[e * B + c[e]] = b;
      c[e]++;
    }
    for (int e = 0; e < NE; ++e) ecnt[e] = c[e];
  }
}

// Phase A: per-chunk local layer-1 scans, h-paired (thread owns h2, h2+1).
template <int BF>
__global__ __launch_bounds__(512, 8) void k_scanA(
    const int* __restrict__ windows, const float* __restrict__ emb,
    const u16* __restrict__ embh, const float* __restrict__ norm1_w,
    const float* __restrict__ decay_logit, const float* __restrict__ invr1,
    float* __restrict__ local1) {
  __shared__ int tok_l[T0];
  __shared__ float iv_l[T0];
  const int b = blockIdx.x / CH, c = blockIdx.x % CH;
  const int tid = threadIdx.x;
  const int h2 = tid * 2;
  if (tid < T0) {
    const int tok = windows[b * S + c * T0 + tid];
    tok_l[tid] = tok << 10;  // tok * H
    iv_l[tid] = invr1[tok];
  }
  const float d1a = 1.f / (1.f + expf(-decay_logit[h2]));
  const float d1b = 1.f / (1.f + expf(-decay_logit[h2 + 1]));
  const float g1a = norm1_w[h2] * (1.f - d1a);
  const float g1b = norm1_w[h2 + 1] * (1.f - d1b);
  __syncthreads();
  float sa = 0.f, sbv = 0.f;
  for (int t0 = 0; t0 < T0; t0 += SB) {
    uint32_t u[SB];
    float2 ef[SB];
#pragma unroll
    for (int k = 0; k < SB; ++k) {
      if constexpr (BF)
        u[k] = *(const uint32_t*)(embh + (size_t)(tok_l[t0 + k] + h2));
      else
        ef[k] = *(const float2*)(emb + (size_t)(tok_l[t0 + k] + h2));
    }
#pragma unroll
    for (int k = 0; k < SB; ++k) {
      const float iv = iv_l[t0 + k];
      const float ea = BF ? bflo(u[k]) : ef[k].x;
      const float eb = BF ? bfhi(u[k]) : ef[k].y;
      sa = sa * d1a + ea * (iv * g1a);
      sbv = sbv * d1b + eb * (iv * g1b);
    }
  }
  *(float2*)(local1 + (size_t)(b * CH + c) * H + h2) = make_float2(sa, sbv);
}

// Phase B: combine chunk locals -> chunk-start states, es1, pooled invRMS.
__global__ __launch_bounds__(1024) void k_scanB(
    const int* __restrict__ windows, const float* __restrict__ emb,
    const float* __restrict__ decay_logit, const float* __restrict__ local1,
    float* __restrict__ s1start, float* __restrict__ es1,
    float* __restrict__ invp) {
  __shared__ float red[16];
  const int b = blockIdx.x, h = threadIdx.x;
  const float d1 = 1.f / (1.f + expf(-decay_logit[h]));
  float dT = d1;
#pragma unroll
  for (int i = 0; i < 6; ++i) dT *= dT;  // d1^64 (= d1^T0)
  float Sv = 0.f;
  for (int c = 0; c < CH; ++c) {
    const size_t idx = (size_t)(b * CH + c) * H + h;
    s1start[idx] = Sv;
    Sv = dT * Sv + local1[idx];
  }
  const int tl = windows[b * S + S - 1];
  const float v = emb[(size_t)tl * H + h] + Sv;
  es1[b * H + h] = v;
  const float q = wave_sum(v * v);
  if ((h & 63) == 0) red[h >> 6] = q;
  __syncthreads();
  if (h == 0) {
    float t = 0.f;
#pragma unroll
    for (int i = 0; i < 16; ++i) t += red[i];
    invp[b] = rsqrtf(t * (1.f / H) + EPS);
  }
}

// K4 v2: expert-grouped matvec.
__global__ __launch_bounds__(256) void k_expert2(
    const float* __restrict__ src, const float* __restrict__ invp,
    const float* __restrict__ n2w, const float* __restrict__ Wl,
    const int* __restrict__ elist, const int* __restrict__ ecnt,
    float* __restrict__ outp) {
  const int e = blockIdx.x >> 6;     // 0..3
  const int dgrp = blockIdx.x & 63;  // 16 rows each
  const int cnt = ecnt[e];
  if (cnt == 0) return;
  const int wave = threadIdx.x >> 6, lane = threadIdx.x & 63;
  const float* W = Wl + (size_t)e * H * H;
  const float4* n2w4 = (const float4*)n2w;
#pragma unroll 1
  for (int i = 0; i < 4; ++i) {
    const int dd = dgrp * 16 + wave * 4 + i;
    const float4* wr4 = (const float4*)(W + (size_t)dd * H);
    float4 w4[4];
#pragma unroll
    for (int j = 0; j < 4; ++j) w4[j] = wr4[lane + 64 * j];
#pragma unroll 1
    for (int bi = 0; bi < cnt; ++bi) {
      const int b = elist[e * B + bi];
      const float4* s4 = (const float4*)(src + b * H);
      float s = 0.f;
#pragma unroll
      for (int j = 0; j < 4; ++j) {
        const float4 sv = s4[lane + 64 * j];
        const float4 nv = n2w4[lane + 64 * j];
        s += w4[j].x * sv.x * nv.x + w4[j].y * sv.y * nv.y +
             w4[j].z * sv.z * nv.z + w4[j].w * sv.w * nv.w;
      }
      s = wave_sum(s);
      if (lane == 0) outp[b * H + dd] = fmaxf(s * invp[b], 0.f);
    }
  }
}

// Fused phase C+D, v2: h-paired, x1 register-resident.
template <int BF>
__global__ __launch_bounds__(512, 8) void k_fuseCD(
    const int* __restrict__ windows, const float* __restrict__ emb,
    const u16* __restrict__ embh, const float* __restrict__ norm1_w,
    const float* __restrict__ decay_logit, const float* __restrict__ invr1,
    const float* __restrict__ s1start, const float* __restrict__ out1,
    float* __restrict__ local2, float* __restrict__ x1last) {
  __shared__ int tok_l[T0];
  __shared__ float iv_l[T0];
  __shared__ float sq[SB][512];
  __shared__ float rinv_l[SB];
  const int b = blockIdx.x / CH, c = blockIdx.x % CH;
  const int tid = threadIdx.x;
  const int h2 = 2 * tid;
  if (tid < T0) {
    const int tok = windows[b * S + c * T0 + tid];
    tok_l[tid] = tok << 10;  // tok * H
    iv_l[tid] = invr1[tok];
  }
  const float d1a = 1.f / (1.f + expf(-decay_logit[h2]));
  const float d1b = 1.f / (1.f + expf(-decay_logit[h2 + 1]));
  const float g1a = norm1_w[h2] * (1.f - d1a);
  const float g1b = norm1_w[h2 + 1] * (1.f - d1b);
  const float d2a = 1.f / (1.f + expf(-decay_logit[H + h2]));
  const float d2b = 1.f / (1.f + expf(-decay_logit[H + h2 + 1]));
  const float g2a = norm1_w[H + h2] * (1.f - d2a);
  const float g2b = norm1_w[H + h2 + 1] * (1.f - d2b);
  const float2 o1 = *(const float2*)(out1 + b * H + h2);
  const float2 s1v = *(const float2*)(s1start + (size_t)(b * CH + c) * H + h2);
  float s1a = s1v.x, s1b = s1v.y;
  float s2a = 0.f, s2b = 0.f;
  __syncthreads();
  const int wv = tid >> 6, lane = tid & 63;
  float x1a[SB], x1b[SB];
  for (int sb = 0; sb < T0 / SB; ++sb) {
    uint32_t u[SB];
    float2 ef[SB];
#pragma unroll
    for (int k = 0; k < SB; ++k) {
      const int t = sb * SB + k;
      if constexpr (BF)
        u[k] = *(const uint32_t*)(embh + (size_t)(tok_l[t] + h2));
      else
        ef[k] = *(const float2*)(emb + (size_t)(tok_l[t] + h2));
    }
#pragma unroll
    for (int k = 0; k < SB; ++k) {
      const float iv = iv_l[sb * SB + k];
      const float ea = BF ? bflo(u[k]) : ef[k].x;
      const float eb = BF ? bfhi(u[k]) : ef[k].y;
      s1a = s1a * d1a + ea * (iv * g1a);
      s1b = s1b * d1b + eb * (iv * g1b);
      x1a[k] = ea + s1a + o1.x;
      x1b[k] = eb + s1b + o1.y;
      sq[k][tid] = x1a[k] * x1a[k] + x1b[k] * x1b[k];
    }
    __syncthreads();
    float ssum = 0.f;
#pragma unroll
    for (int j = 0; j < 8; ++j) ssum += sq[wv][lane + 64 * j];
    ssum = wave_sum(ssum);
    if (lane == 0) rinv_l[wv] = rsqrtf(ssum * (1.f / H) + EPS);
    __syncthreads();
#pragma unroll
    for (int k = 0; k < SB; ++k) {
      const float ra = rinv_l[k];
      s2a = s2a * d2a + x1a[k] * (ra * g2a);
      s2b = s2b * d2b + x1b[k] * (ra * g2b);
    }
  }
  *(float2*)(local2 + (size_t)(b * CH + c) * H + h2) = make_float2(s2a, s2b);
  if (c == CH - 1)
    *(float2*)(x1last + b * H + h2) = make_float2(x1a[SB - 1], x1b[SB - 1]);
}

// Phase E: combine layer-2 chunk locals -> es2 + pooled invRMS.
__global__ __launch_bounds__(1024) void k_scanE(
    const float* __restrict__ decay_logit, const float* __restrict__ local2,
    const float* __restrict__ x1last, float* __restrict__ es2,
    float* __restrict__ invp) {
  __shared__ float red[16];
  const int b = blockIdx.x, h = threadIdx.x;
  const float d2 = 1.f / (1.f + expf(-decay_logit[H + h]));
  float dT = d2;
#pragma unroll
  for (int i = 0; i < 6; ++i) dT *= dT;  // d2^64 (= d2^T0)
  float Sv = 0.f;
  for (int c = 0; c < CH; ++c)
    Sv = dT * Sv + local2[(size_t)(b * CH + c) * H + h];
  const float v = x1last[b * H + h] + Sv;
  es2[b * H + h] = v;
  const float q = wave_sum(v * v);
  if ((h & 63) == 0) red[h >> 6] = q;
  __syncthreads();
  if (h == 0) {
    float t = 0.f;
#pragma unroll
    for (int i = 0; i < 16; ++i) t += red[i];
    invp[32 + b] = rsqrtf(t * (1.f / H) + EPS);
  }
}

// K7: final residual + final RMSNorm -> fstate, emitted as split bf16
// hi/lo pair (hi = truncation, lo = RNE residual). hi+lo == fp32 to 2^-17.
__global__ __launch_bounds__(256) void k_fstate(const float* __restrict__ es2,
    const float* __restrict__ out2, const float* __restrict__ fnw,
    u16* __restrict__ fsth, u16* __restrict__ fstl) {
  __shared__ float red[4];
  const int b = blockIdx.x, tid = threadIdx.x;
  float4 x = ((const float4*)(es2 + b * H))[tid];
  const float4 y = ((const float4*)(out2 + b * H))[tid];
  x.x += y.x; x.y += y.y; x.z += y.z; x.w += y.w;
  float s = x.x * x.x + x.y * x.y + x.z * x.z + x.w * x.w;
  s = wave_sum(s);
  if ((tid & 63) == 0) red[tid >> 6] = s;
  __syncthreads();
  const float ir =
      rsqrtf((red[0] + red[1] + red[2] + red[3]) * (1.f / H) + EPS);
  const float4 w = ((const float4*)fnw)[tid];
  float o[4];
  o[0] = x.x * ir * w.x; o[1] = x.y * ir * w.y;
  o[2] = x.z * ir * w.z; o[3] = x.w * ir * w.w;
  ushort4 hs, ls;
  u16* hp = (u16*)&hs;
  u16* lp = (u16*)&ls;
#pragma unroll
  for (int j = 0; j < 4; ++j) {
    const uint32_t u = fasu(o[j]);
    hp[j] = (u16)(u >> 16);
    lp[j] = f2bf(o[j] - uasf(u & 0xFFFF0000u));
  }
  ((ushort4*)(fsth + b * H))[tid] = hs;
  ((ushort4*)(fstl + b * H))[tid] = ls;
}

// K8 v5: MFMA dual-bf16 GEMM logits = fst @ lm^T, fp32-equivalent accuracy.
// Block = one 16-row vocab tile (938 blocks), 4 waves = split-K quarters.
// A = fst (m = b, pre-split hi/lo bf16, L1-resident), B = lm (n = v, split
// hi/lo on the fly; each element touched exactly once). D = Ah*Bh + Ah*Bl
// + Al*Bh accumulated fp32 in MFMA -> error ~2^-17, same as fp32 path.
// Split-K reduced through 8 KB LDS; writes outp directly (no part/k_comb).
__global__ __launch_bounds__(256) void k_logits(const float* __restrict__ lm,
    const u16* __restrict__ fsth, const u16* __restrict__ fstl,
    float* __restrict__ outp) {
  __shared__ float red[4][2][4][64];  // wave, mtile, reg, lane = 8 KB
  const int tid = threadIdx.x;
  const int w = tid >> 6, l = tid & 63;
  const int ln = l & 15, kg = l >> 4;
  const int v0 = blockIdx.x * 16;
  int r = v0 + ln;
  if (r > V - 1) r = V - 1;
  const int kbase = w * 256 + kg * 8;
  const float* lrow = lm + (size_t)r * H + kbase;
  const u16* fh0 = fsth + (size_t)ln * H + kbase;
  const u16* fh1 = fsth + (size_t)(16 + ln) * H + kbase;
  const u16* fl0 = fstl + (size_t)ln * H + kbase;
  const u16* fl1 = fstl + (size_t)(16 + ln) * H + kbase;
  f32x4 acc0 = {0.f, 0.f, 0.f, 0.f};
  f32x4 acc1 = {0.f, 0.f, 0.f, 0.f};
#pragma unroll 1
  for (int it = 0; it < 8; ++it) {
    const int ko = it * 32;
    const float4 xa = *(const float4*)(lrow + ko);
    const float4 xb = *(const float4*)(lrow + ko + 4);
    union { bf16x8 v; uint32_t u[4]; } Bh, Bl, Ah0, Ah1, Al0, Al1;
    split2(xa.x, xa.y, Bh.u[0], Bl.u[0]);
    split2(xa.z, xa.w, Bh.u[1], Bl.u[1]);
    split2(xb.x, xb.y, Bh.u[2], Bl.u[2]);
    split2(xb.z, xb.w, Bh.u[3], Bl.u[3]);
    *(uint4*)Ah0.u = *(const uint4*)(fh0 + ko);
    *(uint4*)Ah1.u = *(const uint4*)(fh1 + ko);
    *(uint4*)Al0.u = *(const uint4*)(fl0 + ko);
    *(uint4*)Al1.u = *(const uint4*)(fl1 + ko);
    acc0 = __builtin_amdgcn_mfma_f32_16x16x32_bf16(Ah0.v, Bh.v, acc0, 0, 0, 0);
    acc1 = __builtin_amdgcn_mfma_f32_16x16x32_bf16(Ah1.v, Bh.v, acc1, 0, 0, 0);
    acc0 = __builtin_amdgcn_mfma_f32_16x16x32_bf16(Ah0.v, Bl.v, acc0, 0, 0, 0);
    acc1 = __builtin_amdgcn_mfma_f32_16x16x32_bf16(Ah1.v, Bl.v, acc1, 0, 0, 0);
    acc0 = __builtin_amdgcn_mfma_f32_16x16x32_bf16(Al0.v, Bh.v, acc0, 0, 0, 0);
    acc1 = __builtin_amdgcn_mfma_f32_16x16x32_bf16(Al1.v, Bh.v, acc1, 0, 0, 0);
  }
#pragma unroll
  for (int q = 0; q < 4; ++q) {
    red[w][0][q][l] = acc0[q];
    red[w][1][q][l] = acc1[q];
  }
  __syncthreads();
  // 256 threads: (reg = tid>>6, lane = tid&63); sum the 4 k-quarters.
  const int rr = tid >> 6, lane2 = tid & 63;
  const int vv = v0 + (lane2 & 15);
  if (vv < V) {
#pragma unroll
    for (int mt = 0; mt < 2; ++mt) {
      const float s = red[0][mt][rr][lane2] + red[1][mt][rr][lane2] +
                      red[2][mt][rr][lane2] + red[3][mt][rr][lane2];
      const int bb = mt * 16 + 4 * (lane2 >> 4) + rr;
      outp[(size_t)bb * V + vv] = s;
    }
  }
}

extern "C" void kernel_launch(void* const* d_in, const int* in_sizes, int n_in,
                              void* d_out, int out_size, void* d_ws,
                              size_t ws_size, hipStream_t stream) {
  const int* windows = (const int*)d_in[0];
  const int* experts = (const int*)d_in[2];
  const float* emb = (const float*)d_in[3];
  const float* norm1_w = (const float*)d_in[4];
  const float* decay_logit = (const float*)d_in[5];
  const float* norm2_w = (const float*)d_in[6];
  const float* Wexp = (const float*)d_in[7];
  const float* final_norm_w = (const float*)d_in[8];
  const float* lm_head = (const float*)d_in[9];
  float* outp = (float*)d_out;

  float* ws = (float*)d_ws;
  float* invr1 = ws;                       // 15360
  float* local1 = invr1 + 15360;           // B*CH*H
  float* s1start = local1 + B * CH * H;    // B*CH*H
  float* local2 = s1start + B * CH * H;    // B*CH*H
  float* out1 = local2 + B * CH * H;       // B*H
  float* out2 = out1 + B * H;              // B*H
  float* es1 = out2 + B * H;               // B*H
  float* es2 = es1 + B * H;                // B*H
  float* x1last = es2 + B * H;             // B*H
  float* invp = x1last + B * H;            // 64
  int* elist = (int*)(invp + 64);          // NE*B ints
  int* ecnt = elist + NE * B;              // NE ints
  u16* fsth = (u16*)(ecnt + NE);           // B*H u16
  u16* fstl = fsth + B * H;                // B*H u16
  // bf16 emb mirror lives after everything else, if the workspace allows.
  u16* embh = (u16*)(((uintptr_t)(fstl + B * H) + 255) & ~(uintptr_t)255);
  const size_t need = (size_t)((char*)embh - (char*)d_ws) + (size_t)V * H * 2;
  const bool use_bf = ws_size >= need;

  k_vocab<<<(V * 64 + 255) / 256, 256, 0, stream>>>(emb, invr1,
                                                    use_bf ? embh : nullptr);
  k_bucket<<<1, 64, 0, stream>>>(experts, elist, ecnt);
  if (use_bf)
    k_scanA<1><<<B * CH, 512, 0, stream>>>(windows, emb, embh, norm1_w,
                                           decay_logit, invr1, local1);
  else
    k_scanA<0><<<B * CH, 512, 0, stream>>>(windows, emb, embh, norm1_w,
                                           decay_logit, invr1, local1);
  k_scanB<<<B, 1024, 0, stream>>>(windows, emb, decay_logit, local1, s1start,
                                  es1, invp);
  k_expert2<<<NE * 64, 256, 0, stream>>>(es1, invp, norm2_w, Wexp, elist,
                                         ecnt, out1);
  if (use_bf)
    k_fuseCD<1><<<B * CH, 512, 0, stream>>>(windows, emb, embh, norm1_w,
                                            decay_logit, invr1, s1start,
                                            out1, local2, x1last);
  else
    k_fuseCD<0><<<B * CH, 512, 0, stream>>>(windows, emb, embh, norm1_w,
                                            decay_logit, invr1, s1start,
                                            out1, local2, x1last);
  k_scanE<<<B, 1024, 0, stream>>>(decay_logit, local2, x1last, es2, invp);
  k_expert2<<<NE * 64, 256, 0, stream>>>(es2, invp + 32, norm2_w + H,
                                         Wexp + (size_t)NE * H * H, elist,
                                         ecnt, out2);
  k_fstate<<<B, 256, 0, stream>>>(es2, out2, final_norm_w, fsth, fstl);
  k_logits<<<NVT, 256, 0, stream>>>(lm_head, fsth, fstl, outp);
}